// Round 2
// baseline (171.823 us; speedup 1.0000x reference)
//
#include <hip/hip_runtime.h>
#include <math.h>

// JointAttentionMemoryBank via fp16 MFMA.  out = W @ softmax(W^T x / sqrt(D))
//   B=16 N=4096 D=128 M=1536.  fp32 in/out.
// R8: LDS-traffic elimination (R6/R7 post-mortem: kernel is LDS-pipe-bound,
// ~110K of 161K cyc/CU in ds_read+conflicts; NOT 2-phase-stall-bound).
//  - 32x32x16 MFMA everywhere: 2x FLOP per operand byte vs 16x16x32.
//  - Each wave owns a FIXED n-half (nt32 = w&1): its phase-1 x B-fragments
//    (32x128 fp16 = 32 VGPR) are loaded ONCE from global and live in regs all
//    kernel -> phase-1 steady-state LDS reads = 0; xs array deleted entirely.
//  - Phase-2: wave owns 1 d-tile32 (dt32 = w), both n-halves: each P-fragment
//    read feeds 2 MFMA; WD read exactly 1x/block (L2 budget ok: WT 2x + WD 1x
//    = 1.15 MB/block ~ 26 TB/s at 45us < 34.5 ceiling).
//  - Pbuf PPAD=68 f16 (136 B = odd multiple of 8B) + explicit 2x ds_read_b64:
//    uniform 4 lanes per 8B-window on all reads/writes -> conflict-free.
//  - Keep R7 skew: one barrier per 64-m session, p2(q) || p1(q+1), dbuf P.
// LDS total 17.9 KB; __launch_bounds__(256,4) -> 128 VGPR, 4 blocks/CU,
// all 1024 blocks resident. exp2-folded scale in wt. No-max softmax.

#define Bdim 16
#define Ndim 4096
#define Ddim 128
#define Mdim 1536
#define NT 64               // rows (n) per block
#define NTHREADS 256        // 4 waves
#define NSESS 24            // m-sessions (64 m each)
#define PPAD 68             // Pbuf row stride f16 (136 B)
#define NFRAG 24576         // fragments per W array = D*M/8

typedef __attribute__((ext_vector_type(8)))  _Float16 f16x8;   // 4 VGPRs
typedef __attribute__((ext_vector_type(4)))  _Float16 f16x4;   // 8 B
typedef __attribute__((ext_vector_type(16))) float    f32x16;  // 32x32 MFMA C/D

// ---- prep: W (D,M) fp32 -> fragment-ordered fp16 arrays (32x32x16 form) ----
// wt (phase-1 A = W^T, pre-scaled log2e/sqrt(D)):
//   frag f = (mt32*8 + ks)*64 + l ; m = mt32*32 + (l&31), d = ks*16 + (l>>5)*8 + j
// wd (phase-2 A = W):
//   frag f = (dt32*96 + km)*64 + l ; d = dt32*32 + (l&31), m = km*16 + (l>>5)*8 + j
__global__ void jamb_prep(const float* __restrict__ w,
                          _Float16* __restrict__ wt,
                          _Float16* __restrict__ wd) {
    const int tid = blockIdx.x * 256 + threadIdx.x;   // [0, 2*NFRAG)
    const float SC = 0.12751742957f;                  // log2(e)/sqrt(128)
    if (tid < NFRAG) {                                // wt (column gather)
        const int f    = tid;
        const int l    = f & 63;
        const int fs   = f >> 6;
        const int ks   = fs & 7;          // 0..7
        const int mt   = fs >> 3;         // 0..47
        const int m    = mt * 32 + (l & 31);
        const int d0   = ks * 16 + (l >> 5) * 8;
        f16x8 pk;
        #pragma unroll
        for (int j = 0; j < 8; ++j)
            pk[j] = (_Float16)(w[(size_t)(d0 + j) * Mdim + m] * SC);
        *(f16x8*)&wt[(size_t)f * 8] = pk;
    } else {                                          // wd (row-contiguous)
        const int f    = tid - NFRAG;
        const int l    = f & 63;
        const int fs   = f >> 6;
        const int km   = fs % 96;         // 0..95
        const int dt   = fs / 96;         // 0..3
        const int d    = dt * 32 + (l & 31);
        const int m0   = km * 16 + (l >> 5) * 8;
        const float* src = w + (size_t)d * Mdim + m0;
        const float4 v0 = *(const float4*)src;
        const float4 v1 = *(const float4*)(src + 4);
        f16x8 pk;
        pk[0] = (_Float16)v0.x; pk[1] = (_Float16)v0.y;
        pk[2] = (_Float16)v0.z; pk[3] = (_Float16)v0.w;
        pk[4] = (_Float16)v1.x; pk[5] = (_Float16)v1.y;
        pk[6] = (_Float16)v1.z; pk[7] = (_Float16)v1.w;
        *(f16x8*)&wd[(size_t)f * 8] = pk;
    }
}

__global__ __launch_bounds__(NTHREADS, 4)
void jamb_mfma_kernel(const float* __restrict__ x,
                      const _Float16* __restrict__ wt,
                      const _Float16* __restrict__ wd,
                      float* __restrict__ out) {
    __shared__ __align__(16) _Float16 Pbuf[2][NT * PPAD];  // 17408 B (dbuf)
    __shared__ float redsum[2][2][32];                     // 512 B

    const int t    = threadIdx.x;
    const int w    = t >> 6;        // wave 0..3
    const int l    = t & 63;
    const int l31  = l & 31;
    const int hi   = l >> 5;
    const int w1   = w & 1;         // wave's n-half  (nt32, fixed all kernel)
    const int wm   = w >> 1;        // wave's m-tile half within session

    const int blk   = blockIdx.x;
    const int b     = blk >> 6;             // 64 blocks per batch
    const int nbase = (blk & 63) * NT;

    // ---- x B-fragments for this wave's fixed n-half: 8 frags, 32 VGPR,
    //      loaded once from global (fp32 -> fp16), live whole kernel ----
    f16x8 bx[8];
    {
        const float* xb = x + (size_t)(b * Ndim + nbase + w1 * 32 + l31) * Ddim;
        #pragma unroll
        for (int ks = 0; ks < 8; ++ks) {
            const float* s = xb + ks * 16 + hi * 8;
            const float4 v0 = *(const float4*)s;
            const float4 v1 = *(const float4*)(s + 4);
            f16x8 pk;
            pk[0] = (_Float16)v0.x; pk[1] = (_Float16)v0.y;
            pk[2] = (_Float16)v0.z; pk[3] = (_Float16)v0.w;
            pk[4] = (_Float16)v1.x; pk[5] = (_Float16)v1.y;
            pk[6] = (_Float16)v1.z; pk[7] = (_Float16)v1.w;
            bx[ks] = pk;
        }
    }

    const f16x8* WT = (const f16x8*)wt;
    const f16x8* WD = (const f16x8*)wd;

    float ssum = 0.f;                 // per-lane softmax sum for n = w1*32+l31
    f32x16 c0 = (f32x16)(0.f);        // phase-2 acc, n-half 0
    f32x16 c1 = (f32x16)(0.f);        // phase-2 acc, n-half 1
    const int prow = (w1 * 32 + l31) * PPAD;   // P write row (this wave's n)

    // ---- phase 1: one 32x32 S-tile (mt32 = 2q+wm, nt32 = w1); exp; publish ----
    auto p1 = [&](int q) {
        f32x16 acc = (f32x16)(0.f);
        #pragma unroll
        for (int ks = 0; ks < 8; ++ks) {
            const f16x8 fh = WT[(size_t)((2 * q + wm) * 8 + ks) * 64 + l];
            acc = __builtin_amdgcn_mfma_f32_32x32x16_f16(fh, bx[ks], acc, 0, 0, 0);
        }
        _Float16* Pw = &Pbuf[q & 1][0];
        #pragma unroll
        for (int g = 0; g < 4; ++g) {
            const float e0 = exp2f(acc[g * 4 + 0]);   // wt pre-scaled by log2e
            const float e1 = exp2f(acc[g * 4 + 1]);
            const float e2 = exp2f(acc[g * 4 + 2]);
            const float e3 = exp2f(acc[g * 4 + 3]);
            ssum += (e0 + e1) + (e2 + e3);
            f16x4 pk;
            pk[0] = (_Float16)e0; pk[1] = (_Float16)e1;
            pk[2] = (_Float16)e2; pk[3] = (_Float16)e3;
            // m-local col = wm*32 + g*8 + hi*4  (C-row pattern r+8g+4hi)
            *(f16x4*)&Pw[prow + wm * 32 + g * 8 + hi * 4] = pk;
        }
    };

    // ---- phase 2: wave owns dt32 = w, both n-halves; 4 k-steps of 16 m ----
    auto p2 = [&](int q) {
        const _Float16* Pr = &Pbuf[q & 1][0];
        #pragma unroll
        for (int sk = 0; sk < 4; ++sk) {
            const f16x8 a = WD[(size_t)(w * 96 + q * 4 + sk) * 64 + l];
            // n-half 0 fragment: rows l31, k-cols sk*16 + hi*8 .. +7 (2x b64)
            const f16x4 p0lo = *(const f16x4*)&Pr[l31 * PPAD + sk * 16 + hi * 8];
            const f16x4 p0hi = *(const f16x4*)&Pr[l31 * PPAD + sk * 16 + hi * 8 + 4];
            const f16x4 p1lo = *(const f16x4*)&Pr[(32 + l31) * PPAD + sk * 16 + hi * 8];
            const f16x4 p1hi = *(const f16x4*)&Pr[(32 + l31) * PPAD + sk * 16 + hi * 8 + 4];
            const f16x8 pf0 = __builtin_shufflevector(p0lo, p0hi, 0, 1, 2, 3, 4, 5, 6, 7);
            const f16x8 pf1 = __builtin_shufflevector(p1lo, p1hi, 0, 1, 2, 3, 4, 5, 6, 7);
            c0 = __builtin_amdgcn_mfma_f32_32x32x16_f16(a, pf0, c0, 0, 0, 0);
            c1 = __builtin_amdgcn_mfma_f32_32x32x16_f16(a, pf1, c1, 0, 0, 0);
        }
    };

    // ---- skewed pipeline: one barrier per session, p2(q) || p1(q+1) ----
    // p1(q+1) writes buf[(q+1)&1] (last read by p2(q-1), pre-barrier);
    // p2(q) reads buf[q&1] (written by p1(q), pre-barrier).
    p1(0);
    #pragma unroll 1
    for (int q = 0; q < NSESS - 1; ++q) {
        __syncthreads();
        p2(q);
        p1(q + 1);
    }
    __syncthreads();
    p2(NSESS - 1);

    // ---- softmax sums: hi-halves then cross (wm) waves via LDS ----
    ssum += __shfl_xor(ssum, 32, 64);
    if (hi == 0) redsum[w1][wm][l31] = ssum;
    __syncthreads();
    float inv[2];
    #pragma unroll
    for (int tt = 0; tt < 2; ++tt)
        inv[tt] = 1.f / (redsum[tt][0][l31] + redsum[tt][1][l31]);

    // ---- epilogue: d = w*32 + r + 8g + 4hi, n = tt*32 + l31 ----
    #pragma unroll
    for (int tt = 0; tt < 2; ++tt) {
        const float iv = inv[tt];
        const f32x16 cc = tt ? c1 : c0;
        #pragma unroll
        for (int g = 0; g < 4; ++g) {
            float* op = out + (size_t)(b * Ndim + nbase + tt * 32 + l31) * Ddim
                            + w * 32 + g * 8 + hi * 4;
            float4 o;
            o.x = cc[g * 4 + 0] * iv;
            o.y = cc[g * 4 + 1] * iv;
            o.z = cc[g * 4 + 2] * iv;
            o.w = cc[g * 4 + 3] * iv;
            *(float4*)op = o;
        }
    }
}

extern "C" void kernel_launch(void* const* d_in, const int* in_sizes, int n_in,
                              void* d_out, int out_size, void* d_ws, size_t ws_size,
                              hipStream_t stream) {
    const float* x = (const float*)d_in[0];   // (B,N,D)
    const float* w = (const float*)d_in[1];   // (1,D,M)
    float* out = (float*)d_out;
    (void)in_sizes; (void)n_in; (void)out_size; (void)ws_size;

    _Float16* wt = (_Float16*)d_ws;           // 384 KB
    _Float16* wd = wt + Ddim * Mdim;          // 384 KB

    jamb_prep<<<dim3((2 * NFRAG) / 256), dim3(256), 0, stream>>>(w, wt, wd);  // 192 blocks
    jamb_mfma_kernel<<<dim3((Bdim * Ndim) / NT), dim3(NTHREADS), 0, stream>>>(x, wt, wd, out);
}

// Round 3
// 156.889 us; speedup vs baseline: 1.0952x; 1.0952x over previous
//
#include <hip/hip_runtime.h>
#include <math.h>

// JointAttentionMemoryBank via fp16 MFMA.  out = W @ softmax(W^T x / sqrt(D))
//   B=16 N=4096 D=128 M=1536.  fp32 in/out.
// R9: registers-for-occupancy trade. R8 post-mortem: conflict-free layouts
// verified (conflicts 11M->0) but ILP collapsed (1-2 chains) -> latency-bound.
// Conservation law: every MFMA eats 2KB operands; R6's five ~50K-cyc/CU pipes
// (MFMA/LDS/L2/TRANS/VALU) overlapped poorly (wall 162K). R9 removes the LDS
// half (bx in 64 VGPRs, zero p1 LDS reads), keeps conflicts at 0 (144B P
// stride), keeps 6 MFMA chains/wave (acc[2] + c[2][2]), at 2 waves/SIMD
// (256-reg budget, __launch_bounds__(256,2)).
//   NT=128, grid 512 = 2 blocks/CU exact (no tail). Wave (wm,w1) owns
//   m-half of session x n-half of tile. P crosses wm-waves via LDS dbuf,
//   one barrier/session (R7 skew: p2(q) || p1(q+1)).
// All fragment layouts identical to R8 (harness-verified): prep unchanged.
// exp2-folded scale in wt. No-max softmax, P unnormalized fp16, fp32 epilogue.

#define Bdim 16
#define Ndim 4096
#define Ddim 128
#define Mdim 1536
#define NT 128              // rows (n) per block
#define NTHREADS 256        // 4 waves
#define NSESS 24            // m-sessions (64 m each)
#define PPAD 72             // Pbuf row stride f16 (144 B: conflict-free b128/b64)
#define NFRAG 24576         // fragments per W array = D*M/8

typedef __attribute__((ext_vector_type(8)))  _Float16 f16x8;   // 4 VGPRs
typedef __attribute__((ext_vector_type(4)))  _Float16 f16x4;   // 8 B
typedef __attribute__((ext_vector_type(16))) float    f32x16;  // 32x32 MFMA C/D

// ---- prep: W (D,M) fp32 -> fragment-ordered fp16 arrays (32x32x16 form) ----
// wt (phase-1 A = W^T, pre-scaled log2e/sqrt(D)):
//   frag f = (mt32*8 + ks)*64 + l ; m = mt32*32 + (l&31), d = ks*16 + (l>>5)*8 + j
// wd (phase-2 A = W):
//   frag f = (dt32*96 + km)*64 + l ; d = dt32*32 + (l&31), m = km*16 + (l>>5)*8 + j
__global__ void jamb_prep(const float* __restrict__ w,
                          _Float16* __restrict__ wt,
                          _Float16* __restrict__ wd) {
    const int tid = blockIdx.x * 256 + threadIdx.x;   // [0, 2*NFRAG)
    const float SC = 0.12751742957f;                  // log2(e)/sqrt(128)
    if (tid < NFRAG) {                                // wt (column gather)
        const int f    = tid;
        const int l    = f & 63;
        const int fs   = f >> 6;
        const int ks   = fs & 7;          // 0..7
        const int mt   = fs >> 3;         // 0..47
        const int m    = mt * 32 + (l & 31);
        const int d0   = ks * 16 + (l >> 5) * 8;
        f16x8 pk;
        #pragma unroll
        for (int j = 0; j < 8; ++j)
            pk[j] = (_Float16)(w[(size_t)(d0 + j) * Mdim + m] * SC);
        *(f16x8*)&wt[(size_t)f * 8] = pk;
    } else {                                          // wd (row-contiguous)
        const int f    = tid - NFRAG;
        const int l    = f & 63;
        const int fs   = f >> 6;
        const int km   = fs % 96;         // 0..95
        const int dt   = fs / 96;         // 0..3
        const int d    = dt * 32 + (l & 31);
        const int m0   = km * 16 + (l >> 5) * 8;
        const float* src = w + (size_t)d * Mdim + m0;
        const float4 v0 = *(const float4*)src;
        const float4 v1 = *(const float4*)(src + 4);
        f16x8 pk;
        pk[0] = (_Float16)v0.x; pk[1] = (_Float16)v0.y;
        pk[2] = (_Float16)v0.z; pk[3] = (_Float16)v0.w;
        pk[4] = (_Float16)v1.x; pk[5] = (_Float16)v1.y;
        pk[6] = (_Float16)v1.z; pk[7] = (_Float16)v1.w;
        *(f16x8*)&wd[(size_t)f * 8] = pk;
    }
}

__global__ __launch_bounds__(NTHREADS, 2)
void jamb_mfma_kernel(const float* __restrict__ x,
                      const _Float16* __restrict__ wt,
                      const _Float16* __restrict__ wd,
                      float* __restrict__ out) {
    __shared__ __align__(16) _Float16 Pbuf[2][NT * PPAD];  // 36864 B (dbuf)
    __shared__ float redsum[2][2][2][32];                  // [w1][wm][i][l31] 1 KB

    const int t    = threadIdx.x;
    const int w    = t >> 6;        // wave 0..3
    const int l    = t & 63;
    const int l31  = l & 31;
    const int hi   = l >> 5;
    const int wm   = w >> 1;        // m-half owner (session mt32 = 2q+wm; p2 dt pair)
    const int w1   = w & 1;         // n-half owner (nt32 in {2w1, 2w1+1})

    const int blk   = blockIdx.x;
    const int b     = blk >> 5;             // 32 blocks per batch (4096/128)
    const int nbase = (blk & 31) * NT;

    // ---- x B-fragments for this wave's 64-n half: 16 frags = 64 VGPR,
    //      loaded once from global (fp32 -> fp16), live whole kernel ----
    f16x8 bx[2][8];
    #pragma unroll
    for (int i = 0; i < 2; ++i) {
        const float* xr = x + (size_t)(b * Ndim + nbase + (2 * w1 + i) * 32 + l31) * Ddim;
        #pragma unroll
        for (int ks = 0; ks < 8; ++ks) {
            const float* s = xr + ks * 16 + hi * 8;
            const float4 v0 = *(const float4*)s;
            const float4 v1 = *(const float4*)(s + 4);
            f16x8 pk;
            pk[0] = (_Float16)v0.x; pk[1] = (_Float16)v0.y;
            pk[2] = (_Float16)v0.z; pk[3] = (_Float16)v0.w;
            pk[4] = (_Float16)v1.x; pk[5] = (_Float16)v1.y;
            pk[6] = (_Float16)v1.z; pk[7] = (_Float16)v1.w;
            bx[i][ks] = pk;
        }
    }

    const f16x8* WT = (const f16x8*)wt;
    const f16x8* WD = (const f16x8*)wd;

    float ssum[2] = {0.f, 0.f};       // per-lane partial softmax sums (n = (2w1+i)*32+l31)
    f32x16 c[2][2];                   // out acc: [dt-local i2][nt-local j]
    #pragma unroll
    for (int i = 0; i < 2; ++i)
        #pragma unroll
        for (int j = 0; j < 2; ++j) c[i][j] = (f32x16)(0.f);

    // ---- phase 1: one 32x32 m-tile (mt32 = 2q+wm) x both its nt; exp; publish ----
    auto p1 = [&](int q) {
        f32x16 acc[2];
        acc[0] = (f32x16)(0.f);
        acc[1] = (f32x16)(0.f);
        #pragma unroll
        for (int ks = 0; ks < 8; ++ks) {
            const f16x8 fh = WT[(size_t)((2 * q + wm) * 8 + ks) * 64 + l];
            acc[0] = __builtin_amdgcn_mfma_f32_32x32x16_f16(fh, bx[0][ks], acc[0], 0, 0, 0);
            acc[1] = __builtin_amdgcn_mfma_f32_32x32x16_f16(fh, bx[1][ks], acc[1], 0, 0, 0);
        }
        _Float16* Pw = &Pbuf[q & 1][0];
        #pragma unroll
        for (int i = 0; i < 2; ++i) {
            const int nrow = (2 * w1 + i) * 32 + l31;
            #pragma unroll
            for (int g = 0; g < 4; ++g) {
                const float e0 = exp2f(acc[i][g * 4 + 0]);   // wt pre-scaled by log2e
                const float e1 = exp2f(acc[i][g * 4 + 1]);
                const float e2 = exp2f(acc[i][g * 4 + 2]);
                const float e3 = exp2f(acc[i][g * 4 + 3]);
                ssum[i] += (e0 + e1) + (e2 + e3);
                f16x4 pk;
                pk[0] = (_Float16)e0; pk[1] = (_Float16)e1;
                pk[2] = (_Float16)e2; pk[3] = (_Float16)e3;
                // session-local m col = wm*32 + (r&3) + 8g + 4hi, r = 4g..4g+3
                *(f16x4*)&Pw[nrow * PPAD + wm * 32 + g * 8 + hi * 4] = pk;
            }
        }
    };

    // ---- phase 2: wave owns dt in {2wm,2wm+1} x nt in {2w1,2w1+1}; 4 ksteps of 16m ----
    auto p2 = [&](int q) {
        const _Float16* Pr = &Pbuf[q & 1][0];
        #pragma unroll
        for (int sk = 0; sk < 4; ++sk) {
            f16x8 a[2], p[2];
            #pragma unroll
            for (int i2 = 0; i2 < 2; ++i2)
                a[i2] = WD[(size_t)((2 * wm + i2) * 96 + q * 4 + sk) * 64 + l];
            #pragma unroll
            for (int j = 0; j < 2; ++j)
                p[j] = *(const f16x8*)&Pr[((2 * w1 + j) * 32 + l31) * PPAD + sk * 16 + hi * 8];
            #pragma unroll
            for (int i2 = 0; i2 < 2; ++i2)
                #pragma unroll
                for (int j = 0; j < 2; ++j)
                    c[i2][j] = __builtin_amdgcn_mfma_f32_32x32x16_f16(a[i2], p[j], c[i2][j], 0, 0, 0);
        }
    };

    // ---- skewed pipeline: one barrier per session, p2(q) || p1(q+1) ----
    // p1(q+1) writes buf[(q+1)&1] (last read by p2(q-1), pre-barrier);
    // p2(q) reads buf[q&1] (written by p1(q), pre-barrier).
    p1(0);
    #pragma unroll 1
    for (int q = 0; q < NSESS - 1; ++q) {
        __syncthreads();
        p2(q);
        p1(q + 1);
    }
    __syncthreads();
    p2(NSESS - 1);

    // ---- softmax sums: combine hi halves (same n col), then wm waves via LDS ----
    #pragma unroll
    for (int i = 0; i < 2; ++i)
        ssum[i] += __shfl_xor(ssum[i], 32, 64);
    if (hi == 0) {
        #pragma unroll
        for (int i = 0; i < 2; ++i) redsum[w1][wm][i][l31] = ssum[i];
    }
    __syncthreads();
    float inv[2];
    #pragma unroll
    for (int j = 0; j < 2; ++j)
        inv[j] = 1.f / (redsum[w1][0][j][l31] + redsum[w1][1][j][l31]);

    // ---- epilogue: n = nbase + (2w1+j)*32 + l31, d = (2wm+i2)*32 + g*8 + hi*4 + (0..3) ----
    #pragma unroll
    for (int i2 = 0; i2 < 2; ++i2) {
        #pragma unroll
        for (int j = 0; j < 2; ++j) {
            const float iv = inv[j];
            #pragma unroll
            for (int g = 0; g < 4; ++g) {
                float* op = out + (size_t)(b * Ndim + nbase + (2 * w1 + j) * 32 + l31) * Ddim
                                + (2 * wm + i2) * 32 + g * 8 + hi * 4;
                float4 o;
                o.x = c[i2][j][g * 4 + 0] * iv;
                o.y = c[i2][j][g * 4 + 1] * iv;
                o.z = c[i2][j][g * 4 + 2] * iv;
                o.w = c[i2][j][g * 4 + 3] * iv;
                *(float4*)op = o;
            }
        }
    }
}

extern "C" void kernel_launch(void* const* d_in, const int* in_sizes, int n_in,
                              void* d_out, int out_size, void* d_ws, size_t ws_size,
                              hipStream_t stream) {
    const float* x = (const float*)d_in[0];   // (B,N,D)
    const float* w = (const float*)d_in[1];   // (1,D,M)
    float* out = (float*)d_out;
    (void)in_sizes; (void)n_in; (void)out_size; (void)ws_size;

    _Float16* wt = (_Float16*)d_ws;           // 384 KB
    _Float16* wd = wt + Ddim * Mdim;          // 384 KB

    jamb_prep<<<dim3((2 * NFRAG) / 256), dim3(256), 0, stream>>>(w, wt, wd);  // 192 blocks
    jamb_mfma_kernel<<<dim3((Bdim * Ndim) / NT), dim3(NTHREADS), 0, stream>>>(x, wt, wd, out);
}